// Round 8
// baseline (387.381 us; speedup 1.0000x reference)
//
#include <hip/hip_runtime.h>
#include <hip/hip_bf16.h>
#include <math.h>

typedef __bf16 bf16_t;
typedef __attribute__((ext_vector_type(8))) __bf16 bf16x8;
typedef __attribute__((ext_vector_type(4))) float floatx4;

#define SCALE 0.17677669529663689f
#define MFMA __builtin_amdgcn_mfma_f32_16x16x32_bf16

// ---------------------------------------------------------------------------
// prep: one launch for all constant-data preprocessing.
//  blocks [0,6144)     : cb2 = rel-pos bias + shift mask, C-frag ordered
//  blocks [6144,6576)  : qkv_w fp32 -> bf16
//  blocks [6576,6768)  : fold proj into lin: Wf = lin_w @ proj_w (bf16),
//                        bf = lin_b + lin_w @ proj_b
// ---------------------------------------------------------------------------
__global__ __launch_bounds__(256)
void prep(const float* __restrict__ table, const int* __restrict__ rpi,
          const float* __restrict__ mask, const float* __restrict__ qkv_w,
          const float* __restrict__ lw, const float* __restrict__ pw,
          const float* __restrict__ pb, const float* __restrict__ lb,
          bf16_t* __restrict__ cb2, bf16_t* __restrict__ wcvt,
          bf16_t* __restrict__ wfo, float* __restrict__ bfb)
{
    const int blk = blockIdx.x, tid = threadIdx.x;
    if (blk < 6144) {
        int i = blk * 256 + tid;   // 1,572,864 total
        int idx = i & 15, lane = (i >> 4) & 63, mt = (i >> 10) & 3, wh = i >> 12;
        int win = wh / 6, h = wh - win * 6;
        int nt = idx >> 2, r = idx & 3;
        int m = mt * 16 + ((lane >> 4)) * 4 + r;
        int j = nt * 16 + (lane & 15);
        float v;
        if (j >= 49)      v = -1e30f;
        else if (m >= 49) v = 0.0f;
        else              v = table[rpi[m * 49 + j] * 6 + h] + mask[win * 2401 + m * 49 + j];
        cb2[i] = (bf16_t)v;
    } else if (blk < 6576) {
        int i = (blk - 6144) * 256 + tid;   // 110592 total, exact
        wcvt[i] = (bf16_t)qkv_w[i];
    } else {
        int o = blk - 6576, i = tid;        // 192 x 192
        if (i < 192) {
            float acc = 0.f;
            for (int c = 0; c < 192; ++c)
                acc += lw[o * 192 + c] * pw[c * 192 + i];
            wfo[o * 192 + i] = (bf16_t)acc;
            if (i == 0) {
                float b = lb[o];
                for (int c = 0; c < 192; ++c) b += lw[o * 192 + c] * pb[c];
                bfb[o] = b;
            }
        }
    }
}

// ---------------------------------------------------------------------------
// MEGAKERNEL, TWO WINDOWS PER BLOCK (768 thr = 12 waves).
// Empirical law (r0/r1/r3/r4/r6): the CU hosts exactly ONE workgroup
// regardless of LDS/VGPR, but a 768-thr workgroup gets 12 waves resident
// (r3: 35% occupancy).  So pack 2 independent windows per block: waves 0-5
// -> window 2*blk, waves 6-11 -> window 2*blk+1.  Per-wave code identical
// to the r6 megakernel (best per-wave efficiency); coupling = 4 symmetric
// barriers only.
//
// LDS per window 30720 bf16 (61.4 KB): 6 head regions [q 64x40 | k 64x40],
// overlaid by P 64x72 / vT 32x72 (wave-private).  XL [64][200] (ctx/X tile,
// 25.6 KB) OVERLAYS head regions 0..2: XL live only in phase 0 (LN->xf pull)
// and the ctx->lin phase; R live only in between.  Barriers:
//  (1) X staged  (2) xf pulled -> R may overwrite XL
//  (3) PV done (all R reads) -> ctx may overwrite R   (4) ctx staged.
// Total LDS 2 x 61440 B = 122,880 B (fits 160 KB; 128 KB static precedent).
// ---------------------------------------------------------------------------
__global__ __launch_bounds__(768)
void fused_window(const float* __restrict__ inp, const float* __restrict__ g,
                  const float* __restrict__ bta, const bf16_t* __restrict__ wcvt,
                  const float* __restrict__ qkv_b, const bf16_t* __restrict__ cb2,
                  const bf16_t* __restrict__ wfo, const float* __restrict__ bfb,
                  float* __restrict__ out)
{
    __shared__ __align__(16) bf16_t lds[61440];      // 2 windows x 30720 bf16
    const int tid = threadIdx.x;
    const int wv = tid >> 6;                          // 0..11
    const int wwin = wv >= 6 ? 1 : 0;                 // window slot in block
    const int h = wv - wwin * 6;                      // head 0..5
    const int lane = tid & 63;
    const int quad = lane >> 4, lr = lane & 15;
    const int w = blockIdx.x * 2 + wwin;              // window id 0..2047
    const int wh = (w & 63) * 6 + h;
    bf16_t* base = lds + wwin * 30720;
    bf16_t* XL = base;                                // [64][200], overlays R0..R2
    bf16_t* R  = base + h * 5120;                     // per-head region

    const int b = w >> 6, widx = w & 63;
    const int whh = widx >> 3, www = widx & 7;

    // ---- Phase 0: LayerNorm + gather (shift/partition) into XL ----
    {
        float g0 = g[lane], g1 = g[lane + 64], g2 = g[lane + 128];
        float b0 = bta[lane], b1 = bta[lane + 64], b2 = bta[lane + 128];
        for (int t = h; t < 49; t += 6) {
            int ii = t / 7, jj = t - ii * 7;
            int hh2 = whh * 7 + ii + 3; if (hh2 >= 56) hh2 -= 56;
            int ww2 = www * 7 + jj + 3; if (ww2 >= 56) ww2 -= 56;
            const float* row = inp + ((size_t)(b * 3136 + hh2 * 56 + ww2)) * 192;
            float v0 = row[lane], v1 = row[lane + 64], v2 = row[lane + 128];
            float s = v0 + v1 + v2;
            float sq = v0 * v0 + v1 * v1 + v2 * v2;
#pragma unroll
            for (int off = 32; off > 0; off >>= 1) {
                s  += __shfl_down(s, off);
                sq += __shfl_down(sq, off);
            }
            s = __shfl(s, 0); sq = __shfl(sq, 0);
            float mu  = s * (1.0f / 192.0f);
            float var = sq * (1.0f / 192.0f) - mu * mu;
            float inv = rsqrtf(var + 1e-5f);
            XL[t * 200 + lane]       = (bf16_t)((v0 - mu) * inv * g0 + b0);
            XL[t * 200 + lane + 64]  = (bf16_t)((v1 - mu) * inv * g1 + b1);
            XL[t * 200 + lane + 128] = (bf16_t)((v2 - mu) * inv * g2 + b2);
        }
        for (int rr = 49 + h; rr < 64; rr += 6)
            for (int j = lane; j < 192; j += 64)
                XL[rr * 200 + j] = (bf16_t)0.f;
    }
    __syncthreads();   // (1) X staged

    // ---- X A-fragments into registers; then XL is dead ----
    bf16x8 xf[4][6];
#pragma unroll
    for (int mt = 0; mt < 4; ++mt)
#pragma unroll
        for (int ks = 0; ks < 6; ++ks)
            xf[mt][ks] = *(const bf16x8*)&XL[(mt * 16 + lr) * 200 + ks * 32 + quad * 8];
    __syncthreads();   // (2) all xf pulled; R may overwrite XL

    // ---- Phase A1: q,k = X @ Wq,Wk  (64 tok x 64 cols) ----
    floatx4 acc[4][4];
#pragma unroll
    for (int mt = 0; mt < 4; ++mt)
#pragma unroll
        for (int nt = 0; nt < 4; ++nt) acc[mt][nt] = floatx4{0.f,0.f,0.f,0.f};

#pragma unroll
    for (int ks = 0; ks < 6; ++ks) {
        bf16x8 wf0 = *(const bf16x8*)(wcvt + (size_t)(h * 32 + lr) * 192 + ks * 32 + quad * 8);
        bf16x8 wf1 = *(const bf16x8*)(wcvt + (size_t)(h * 32 + 16 + lr) * 192 + ks * 32 + quad * 8);
        bf16x8 wf2 = *(const bf16x8*)(wcvt + (size_t)(192 + h * 32 + lr) * 192 + ks * 32 + quad * 8);
        bf16x8 wf3 = *(const bf16x8*)(wcvt + (size_t)(192 + h * 32 + 16 + lr) * 192 + ks * 32 + quad * 8);
#pragma unroll
        for (int mt = 0; mt < 4; ++mt) {
            acc[mt][0] = MFMA(xf[mt][ks], wf0, acc[mt][0], 0, 0, 0);
            acc[mt][1] = MFMA(xf[mt][ks], wf1, acc[mt][1], 0, 0, 0);
            acc[mt][2] = MFMA(xf[mt][ks], wf2, acc[mt][2], 0, 0, 0);
            acc[mt][3] = MFMA(xf[mt][ks], wf3, acc[mt][3], 0, 0, 0);
        }
    }
    {
        float bq0 = qkv_b[h * 32 + lr],       bq1 = qkv_b[h * 32 + 16 + lr];
        float bk0 = qkv_b[192 + h * 32 + lr], bk1 = qkv_b[192 + h * 32 + 16 + lr];
#pragma unroll
        for (int mt = 0; mt < 4; ++mt)
#pragma unroll
            for (int r = 0; r < 4; ++r) {
                int tok = mt * 16 + quad * 4 + r;
                R[tok * 40 + lr]             = (bf16_t)((acc[mt][0][r] + bq0) * SCALE);
                R[tok * 40 + 16 + lr]        = (bf16_t)((acc[mt][1][r] + bq1) * SCALE);
                R[2560 + tok * 40 + lr]      = (bf16_t)(acc[mt][2][r] + bk0);
                R[2560 + tok * 40 + 16 + lr] = (bf16_t)(acc[mt][3][r] + bk1);
            }
    }

    // ---- QK^T (64x64, K=32) ----
    bf16x8 qf[4], kf[4];
#pragma unroll
    for (int t = 0; t < 4; ++t) {
        qf[t] = *(const bf16x8*)&R[(t * 16 + lr) * 40 + quad * 8];
        kf[t] = *(const bf16x8*)&R[2560 + (t * 16 + lr) * 40 + quad * 8];
    }
    floatx4 s[4][4];
#pragma unroll
    for (int mt = 0; mt < 4; ++mt)
#pragma unroll
        for (int nt = 0; nt < 4; ++nt) s[mt][nt] = floatx4{0.f,0.f,0.f,0.f};
#pragma unroll
    for (int mt = 0; mt < 4; ++mt)
#pragma unroll
        for (int nt = 0; nt < 4; ++nt)
            s[mt][nt] = MFMA(qf[mt], kf[nt], s[mt][nt], 0, 0, 0);

    // bias + mask (C-frag ordered)
    const bf16_t* cb = cb2 + (((size_t)wh * 4) * 64 + lane) * 16;
#pragma unroll
    for (int mt = 0; mt < 4; ++mt) {
        bf16x8 c0 = *(const bf16x8*)(cb + (size_t)mt * 1024);
        bf16x8 c1 = *(const bf16x8*)(cb + (size_t)mt * 1024 + 8);
#pragma unroll
        for (int r = 0; r < 4; ++r) {
            s[mt][0][r] += (float)c0[r];
            s[mt][1][r] += (float)c0[4 + r];
            s[mt][2][r] += (float)c1[r];
            s[mt][3][r] += (float)c1[4 + r];
        }
    }

    // in-register row softmax (row spread over 16 lr lanes x 4 nt regs)
#pragma unroll
    for (int mt = 0; mt < 4; ++mt) {
#pragma unroll
        for (int r = 0; r < 4; ++r) {
            float mx = fmaxf(fmaxf(s[mt][0][r], s[mt][1][r]),
                             fmaxf(s[mt][2][r], s[mt][3][r]));
#pragma unroll
            for (int off = 1; off < 16; off <<= 1)
                mx = fmaxf(mx, __shfl_xor(mx, off));
            float sum = 0.f;
#pragma unroll
            for (int nt = 0; nt < 4; ++nt) {
                float e = __expf(s[mt][nt][r] - mx);
                s[mt][nt][r] = e; sum += e;
            }
#pragma unroll
            for (int off = 1; off < 16; off <<= 1)
                sum += __shfl_xor(sum, off);
            float inv = 1.0f / sum;
#pragma unroll
            for (int nt = 0; nt < 4; ++nt) s[mt][nt][r] *= inv;
        }
    }

    // ---- P -> LDS (overwrites q/k; wave-private), pull A-frags of P ----
#pragma unroll
    for (int mt = 0; mt < 4; ++mt)
#pragma unroll
        for (int nt = 0; nt < 4; ++nt)
#pragma unroll
            for (int r = 0; r < 4; ++r)
                R[(mt * 16 + quad * 4 + r) * 72 + nt * 16 + lr] = (bf16_t)s[mt][nt][r];
    bf16x8 pf[4][2];
#pragma unroll
    for (int mt = 0; mt < 4; ++mt)
#pragma unroll
        for (int kt = 0; kt < 2; ++kt)
            pf[mt][kt] = *(const bf16x8*)&R[(mt * 16 + lr) * 72 + kt * 32 + quad * 8];

    // ---- Phase A2: v = X @ Wv (64 tok x 32 d) ----
    floatx4 va[4][2];
#pragma unroll
    for (int mt = 0; mt < 4; ++mt) { va[mt][0] = floatx4{0.f,0.f,0.f,0.f}; va[mt][1] = floatx4{0.f,0.f,0.f,0.f}; }
#pragma unroll
    for (int ks = 0; ks < 6; ++ks) {
        bf16x8 wv0 = *(const bf16x8*)(wcvt + (size_t)(384 + h * 32 + lr) * 192 + ks * 32 + quad * 8);
        bf16x8 wv1 = *(const bf16x8*)(wcvt + (size_t)(384 + h * 32 + 16 + lr) * 192 + ks * 32 + quad * 8);
#pragma unroll
        for (int mt = 0; mt < 4; ++mt) {
            va[mt][0] = MFMA(xf[mt][ks], wv0, va[mt][0], 0, 0, 0);
            va[mt][1] = MFMA(xf[mt][ks], wv1, va[mt][1], 0, 0, 0);
        }
    }
    // vT into P region rows 0..31 (P frags already in regs; DS in-order)
    {
        float bv0 = qkv_b[384 + h * 32 + lr], bv1 = qkv_b[384 + h * 32 + 16 + lr];
#pragma unroll
        for (int mt = 0; mt < 4; ++mt)
#pragma unroll
            for (int r = 0; r < 4; ++r) {
                int tok = mt * 16 + quad * 4 + r;
                R[lr * 72 + tok]        = (bf16_t)(va[mt][0][r] + bv0);
                R[(16 + lr) * 72 + tok] = (bf16_t)(va[mt][1][r] + bv1);
            }
    }

    // ---- PV (64 x 32, K=64) ----
    bf16x8 vf[2][2];
#pragma unroll
    for (int nt = 0; nt < 2; ++nt)
#pragma unroll
        for (int kt = 0; kt < 2; ++kt)
            vf[nt][kt] = *(const bf16x8*)&R[(nt * 16 + lr) * 72 + kt * 32 + quad * 8];
    floatx4 c[4][2];
#pragma unroll
    for (int mt = 0; mt < 4; ++mt) { c[mt][0] = floatx4{0.f,0.f,0.f,0.f}; c[mt][1] = floatx4{0.f,0.f,0.f,0.f}; }
#pragma unroll
    for (int mt = 0; mt < 4; ++mt)
#pragma unroll
        for (int nt = 0; nt < 2; ++nt) {
            c[mt][nt] = MFMA(pf[mt][0], vf[nt][0], c[mt][nt], 0, 0, 0);
            c[mt][nt] = MFMA(pf[mt][1], vf[nt][1], c[mt][nt], 0, 0, 0);
        }
    __syncthreads();   // (3) all R reads done; ctx may overwrite R/XL

    // ---- ctx -> XL [64][200] ----
#pragma unroll
    for (int mt = 0; mt < 4; ++mt)
#pragma unroll
        for (int nt = 0; nt < 2; ++nt)
#pragma unroll
            for (int r = 0; r < 4; ++r)
                XL[(mt * 16 + quad * 4 + r) * 200 + h * 32 + nt * 16 + lr] = (bf16_t)c[mt][nt][r];
    __syncthreads();   // (4) ctx of all heads staged

    // ---- folded lin: out = resid + gelu(ctx @ Wf^T + bf), cols [h*32,h*32+32) ----
    floatx4 pr[4][2];
#pragma unroll
    for (int mt = 0; mt < 4; ++mt) { pr[mt][0] = floatx4{0.f,0.f,0.f,0.f}; pr[mt][1] = floatx4{0.f,0.f,0.f,0.f}; }
#pragma unroll
    for (int ks = 0; ks < 6; ++ks) {
        bf16x8 w0 = *(const bf16x8*)(wfo + (size_t)(h * 32 + lr) * 192 + ks * 32 + quad * 8);
        bf16x8 w1 = *(const bf16x8*)(wfo + (size_t)(h * 32 + 16 + lr) * 192 + ks * 32 + quad * 8);
#pragma unroll
        for (int mt = 0; mt < 4; ++mt) {
            bf16x8 af = *(const bf16x8*)&XL[(mt * 16 + lr) * 200 + ks * 32 + quad * 8];
            pr[mt][0] = MFMA(af, w0, pr[mt][0], 0, 0, 0);
            pr[mt][1] = MFMA(af, w1, pr[mt][1], 0, 0, 0);
        }
    }
    // epilogue: bias + gelu + residual, window-reverse + unshift scatter
    {
        float pb0 = bfb[h * 32 + lr], pb1 = bfb[h * 32 + 16 + lr];
#pragma unroll
        for (int mt = 0; mt < 4; ++mt)
#pragma unroll
            for (int r = 0; r < 4; ++r) {
                int m = mt * 16 + quad * 4 + r;
                if (m < 49) {
                    int ii = m / 7, jj = m - ii * 7;
                    int hh2 = whh * 7 + ii + 3; if (hh2 >= 56) hh2 -= 56;
                    int ww2 = www * 7 + jj + 3; if (ww2 >= 56) ww2 -= 56;
                    size_t base2 = ((size_t)(b * 3136 + hh2 * 56 + ww2)) * 192 + h * 32;
                    float v0 = pr[mt][0][r] + pb0;
                    float v1 = pr[mt][1][r] + pb1;
                    float gx0 = 0.5f * v0 * (1.0f + erff(v0 * 0.70710678118654752f));
                    float gx1 = 0.5f * v1 * (1.0f + erff(v1 * 0.70710678118654752f));
                    out[base2 + lr]      = inp[base2 + lr]      + gx0;
                    out[base2 + 16 + lr] = inp[base2 + 16 + lr] + gx1;
                }
            }
    }
}

// ---------------------------------------------------------------------------
extern "C" void kernel_launch(void* const* d_in, const int* in_sizes, int n_in,
                              void* d_out, int out_size, void* d_ws, size_t ws_size,
                              hipStream_t stream)
{
    const float* inp    = (const float*)d_in[0];
    const float* mask   = (const float*)d_in[1];
    const float* g      = (const float*)d_in[2];
    const float* bta    = (const float*)d_in[3];
    const float* qkv_w  = (const float*)d_in[4];
    const float* qkv_b  = (const float*)d_in[5];
    const float* table  = (const float*)d_in[6];
    const int*   rpi    = (const int*)d_in[7];
    const float* proj_w = (const float*)d_in[8];
    const float* proj_b = (const float*)d_in[9];
    const float* lin_w  = (const float*)d_in[10];
    const float* lin_b  = (const float*)d_in[11];
    float* out = (float*)d_out;

    char* ws = (char*)d_ws;
    bf16_t* wcvt = (bf16_t*)(ws);                 // qkv bf16: 221,184 B
    bf16_t* wfo  = wcvt + 110592;                 // folded Wf: 73,728 B
    float*  bfb  = (float*)(ws + 294912);         // folded bias: 768 B
    bf16_t* cb2  = (bf16_t*)(ws + 300032);        // 3,145,728 B (16B aligned)

    prep<<<6768, 256, 0, stream>>>(table, rpi, mask, qkv_w, lin_w, proj_w,
                                   proj_b, lin_b, cb2, wcvt, wfo, bfb);
    fused_window<<<1024, 768, 0, stream>>>(inp, g, bta, wcvt, qkv_b, cb2,
                                           wfo, bfb, out);
}

// Round 9
// 298.339 us; speedup vs baseline: 1.2985x; 1.2985x over previous
//
#include <hip/hip_runtime.h>
#include <hip/hip_bf16.h>
#include <math.h>

typedef __bf16 bf16_t;
typedef __attribute__((ext_vector_type(8))) __bf16 bf16x8;
typedef __attribute__((ext_vector_type(4))) float floatx4;

#define SCALE 0.17677669529663689f
#define MFMA __builtin_amdgcn_mfma_f32_16x16x32_bf16

// ---------------------------------------------------------------------------
// prep: one launch for all constant-data preprocessing.
//  blocks [0,6144)     : cb2 = rel-pos bias + shift mask, C-frag ordered
//  blocks [6144,6576)  : qkv_w fp32 -> bf16
//  blocks [6576,6768)  : fold proj into lin: Wf = lin_w @ proj_w (bf16),
//                        bf = lin_b + lin_w @ proj_b
// ---------------------------------------------------------------------------
__global__ __launch_bounds__(256)
void prep(const float* __restrict__ table, const int* __restrict__ rpi,
          const float* __restrict__ mask, const float* __restrict__ qkv_w,
          const float* __restrict__ lw, const float* __restrict__ pw,
          const float* __restrict__ pb, const float* __restrict__ lb,
          bf16_t* __restrict__ cb2, bf16_t* __restrict__ wcvt,
          bf16_t* __restrict__ wfo, float* __restrict__ bfb)
{
    const int blk = blockIdx.x, tid = threadIdx.x;
    if (blk < 6144) {
        int i = blk * 256 + tid;   // 1,572,864 total
        int idx = i & 15, lane = (i >> 4) & 63, mt = (i >> 10) & 3, wh = i >> 12;
        int win = wh / 6, h = wh - win * 6;
        int nt = idx >> 2, r = idx & 3;
        int m = mt * 16 + ((lane >> 4)) * 4 + r;
        int j = nt * 16 + (lane & 15);
        float v;
        if (j >= 49)      v = -1e30f;
        else if (m >= 49) v = 0.0f;
        else              v = table[rpi[m * 49 + j] * 6 + h] + mask[win * 2401 + m * 49 + j];
        cb2[i] = (bf16_t)v;
    } else if (blk < 6576) {
        int i = (blk - 6144) * 256 + tid;   // 110592 total, exact
        wcvt[i] = (bf16_t)qkv_w[i];
    } else {
        int o = blk - 6576, i = tid;        // 192 x 192
        if (i < 192) {
            float acc = 0.f;
            for (int c = 0; c < 192; ++c)
                acc += lw[o * 192 + c] * pw[c * 192 + i];
            wfo[o * 192 + i] = (bf16_t)acc;
            if (i == 0) {
                float b = lb[o];
                for (int c = 0; c < 192; ++c) b += lw[o * 192 + c] * pb[c];
                bfb[o] = b;
            }
        }
    }
}

// ---------------------------------------------------------------------------
// MEGAKERNEL, TWO WINDOWS PER BLOCK (768 thr = 12 waves), SPILL-FREE.
// r8 lesson: overlaying the X tile (XL) with the attention regions (R)
// forced the compiler to HOLD all X fragments -> ~370 MB scratch spill
// traffic (WRITE 450 MB).  Fix: persistent per-window XL, X fragments
// RE-READ from LDS per ks in each GEMM phase (A1/A2/lin); no xf array.
// Peak reg liveness ~110 -> __launch_bounds__(768,3) (cap 170), no spills.
//
// LDS budget trick: XL holds only the 49 REAL tokens ([49][200] bf16);
// fragment rows >=49 are predicated to zero at load (MFMA garbage stays in
// its own C row; rows >=49 never stored).  Per window:
//   XL 9800 + R 6x5120 = 40,520 bf16;  x2 windows = 162,080 B <= 160 KB.
// R per head: [q 64x40 | k 64x40] -> P 64x72 / vT 32x72 (wave-private,
// DS in-order).  Barriers: (1) X staged  (2) PV done -> ctx may write XL
// (3) ctx staged -> lin reads.
// ---------------------------------------------------------------------------
__global__ __launch_bounds__(768, 3)
void fused_window(const float* __restrict__ inp, const float* __restrict__ g,
                  const float* __restrict__ bta, const bf16_t* __restrict__ wcvt,
                  const float* __restrict__ qkv_b, const bf16_t* __restrict__ cb2,
                  const bf16_t* __restrict__ wfo, const float* __restrict__ bfb,
                  float* __restrict__ out)
{
    __shared__ __align__(16) bf16_t lds[81040];      // 2 x 40,520 bf16
    const int tid = threadIdx.x;
    const int wv = tid >> 6;                          // 0..11
    const int wwin = wv >= 6 ? 1 : 0;                 // window slot in block
    const int h = wv - wwin * 6;                      // head 0..5
    const int lane = tid & 63;
    const int quad = lane >> 4, lr = lane & 15;
    const int w = blockIdx.x * 2 + wwin;              // window id 0..2047
    const int wh = (w & 63) * 6 + h;
    bf16_t* base = lds + wwin * 40520;
    bf16_t* XL = base;                                // [49][200]
    bf16_t* R  = base + 9800 + h * 5120;              // per-head region

    const int b = w >> 6, widx = w & 63;
    const int whh = widx >> 3, www = widx & 7;

    // predicated X-fragment load: rows >= 49 read as zero
    auto ldx = [&](int mt, int ks) -> bf16x8 {
        bf16x8 z = {};
        int row = mt * 16 + lr;
        if (row < 49) z = *(const bf16x8*)&XL[row * 200 + ks * 32 + quad * 8];
        return z;
    };

    // ---- Phase 0: LayerNorm + gather (shift/partition) into XL[49][200] ----
    {
        float g0 = g[lane], g1 = g[lane + 64], g2 = g[lane + 128];
        float b0 = bta[lane], b1 = bta[lane + 64], b2 = bta[lane + 128];
        for (int t = h; t < 49; t += 6) {
            int ii = t / 7, jj = t - ii * 7;
            int hh2 = whh * 7 + ii + 3; if (hh2 >= 56) hh2 -= 56;
            int ww2 = www * 7 + jj + 3; if (ww2 >= 56) ww2 -= 56;
            const float* row = inp + ((size_t)(b * 3136 + hh2 * 56 + ww2)) * 192;
            float v0 = row[lane], v1 = row[lane + 64], v2 = row[lane + 128];
            float s = v0 + v1 + v2;
            float sq = v0 * v0 + v1 * v1 + v2 * v2;
#pragma unroll
            for (int off = 32; off > 0; off >>= 1) {
                s  += __shfl_down(s, off);
                sq += __shfl_down(sq, off);
            }
            s = __shfl(s, 0); sq = __shfl(sq, 0);
            float mu  = s * (1.0f / 192.0f);
            float var = sq * (1.0f / 192.0f) - mu * mu;
            float inv = rsqrtf(var + 1e-5f);
            XL[t * 200 + lane]       = (bf16_t)((v0 - mu) * inv * g0 + b0);
            XL[t * 200 + lane + 64]  = (bf16_t)((v1 - mu) * inv * g1 + b1);
            XL[t * 200 + lane + 128] = (bf16_t)((v2 - mu) * inv * g2 + b2);
        }
    }
    __syncthreads();   // (1) X staged

    // ---- Phase A1: q,k = X @ Wq,Wk  (64 tok x 64 cols); X from LDS ----
    floatx4 acc[4][4];
#pragma unroll
    for (int mt = 0; mt < 4; ++mt)
#pragma unroll
        for (int nt = 0; nt < 4; ++nt) acc[mt][nt] = floatx4{0.f,0.f,0.f,0.f};

#pragma unroll
    for (int ks = 0; ks < 6; ++ks) {
        bf16x8 wf0 = *(const bf16x8*)(wcvt + (size_t)(h * 32 + lr) * 192 + ks * 32 + quad * 8);
        bf16x8 wf1 = *(const bf16x8*)(wcvt + (size_t)(h * 32 + 16 + lr) * 192 + ks * 32 + quad * 8);
        bf16x8 wf2 = *(const bf16x8*)(wcvt + (size_t)(192 + h * 32 + lr) * 192 + ks * 32 + quad * 8);
        bf16x8 wf3 = *(const bf16x8*)(wcvt + (size_t)(192 + h * 32 + 16 + lr) * 192 + ks * 32 + quad * 8);
#pragma unroll
        for (int mt = 0; mt < 4; ++mt) {
            bf16x8 xk = ldx(mt, ks);
            acc[mt][0] = MFMA(xk, wf0, acc[mt][0], 0, 0, 0);
            acc[mt][1] = MFMA(xk, wf1, acc[mt][1], 0, 0, 0);
            acc[mt][2] = MFMA(xk, wf2, acc[mt][2], 0, 0, 0);
            acc[mt][3] = MFMA(xk, wf3, acc[mt][3], 0, 0, 0);
        }
    }
    {
        float bq0 = qkv_b[h * 32 + lr],       bq1 = qkv_b[h * 32 + 16 + lr];
        float bk0 = qkv_b[192 + h * 32 + lr], bk1 = qkv_b[192 + h * 32 + 16 + lr];
#pragma unroll
        for (int mt = 0; mt < 4; ++mt)
#pragma unroll
            for (int r = 0; r < 4; ++r) {
                int tok = mt * 16 + quad * 4 + r;
                R[tok * 40 + lr]             = (bf16_t)((acc[mt][0][r] + bq0) * SCALE);
                R[tok * 40 + 16 + lr]        = (bf16_t)((acc[mt][1][r] + bq1) * SCALE);
                R[2560 + tok * 40 + lr]      = (bf16_t)(acc[mt][2][r] + bk0);
                R[2560 + tok * 40 + 16 + lr] = (bf16_t)(acc[mt][3][r] + bk1);
            }
    }

    // ---- QK^T (64x64, K=32) ----
    bf16x8 qf[4], kf[4];
#pragma unroll
    for (int t = 0; t < 4; ++t) {
        qf[t] = *(const bf16x8*)&R[(t * 16 + lr) * 40 + quad * 8];
        kf[t] = *(const bf16x8*)&R[2560 + (t * 16 + lr) * 40 + quad * 8];
    }
    floatx4 s[4][4];
#pragma unroll
    for (int mt = 0; mt < 4; ++mt)
#pragma unroll
        for (int nt = 0; nt < 4; ++nt) s[mt][nt] = floatx4{0.f,0.f,0.f,0.f};
#pragma unroll
    for (int mt = 0; mt < 4; ++mt)
#pragma unroll
        for (int nt = 0; nt < 4; ++nt)
            s[mt][nt] = MFMA(qf[mt], kf[nt], s[mt][nt], 0, 0, 0);

    // bias + mask (C-frag ordered)
    const bf16_t* cb = cb2 + (((size_t)wh * 4) * 64 + lane) * 16;
#pragma unroll
    for (int mt = 0; mt < 4; ++mt) {
        bf16x8 c0 = *(const bf16x8*)(cb + (size_t)mt * 1024);
        bf16x8 c1 = *(const bf16x8*)(cb + (size_t)mt * 1024 + 8);
#pragma unroll
        for (int r = 0; r < 4; ++r) {
            s[mt][0][r] += (float)c0[r];
            s[mt][1][r] += (float)c0[4 + r];
            s[mt][2][r] += (float)c1[r];
            s[mt][3][r] += (float)c1[4 + r];
        }
    }

    // in-register row softmax (row spread over 16 lr lanes x 4 nt regs)
#pragma unroll
    for (int mt = 0; mt < 4; ++mt) {
#pragma unroll
        for (int r = 0; r < 4; ++r) {
            float mx = fmaxf(fmaxf(s[mt][0][r], s[mt][1][r]),
                             fmaxf(s[mt][2][r], s[mt][3][r]));
#pragma unroll
            for (int off = 1; off < 16; off <<= 1)
                mx = fmaxf(mx, __shfl_xor(mx, off));
            float sum = 0.f;
#pragma unroll
            for (int nt = 0; nt < 4; ++nt) {
                float e = __expf(s[mt][nt][r] - mx);
                s[mt][nt][r] = e; sum += e;
            }
#pragma unroll
            for (int off = 1; off < 16; off <<= 1)
                sum += __shfl_xor(sum, off);
            float inv = 1.0f / sum;
#pragma unroll
            for (int nt = 0; nt < 4; ++nt) s[mt][nt][r] *= inv;
        }
    }

    // ---- P -> LDS (overwrites q/k; wave-private), pull A-frags of P ----
#pragma unroll
    for (int mt = 0; mt < 4; ++mt)
#pragma unroll
        for (int nt = 0; nt < 4; ++nt)
#pragma unroll
            for (int r = 0; r < 4; ++r)
                R[(mt * 16 + quad * 4 + r) * 72 + nt * 16 + lr] = (bf16_t)s[mt][nt][r];
    bf16x8 pf[4][2];
#pragma unroll
    for (int mt = 0; mt < 4; ++mt)
#pragma unroll
        for (int kt = 0; kt < 2; ++kt)
            pf[mt][kt] = *(const bf16x8*)&R[(mt * 16 + lr) * 72 + kt * 32 + quad * 8];

    // ---- Phase A2: v = X @ Wv (64 tok x 32 d); X re-read from LDS ----
    floatx4 va[4][2];
#pragma unroll
    for (int mt = 0; mt < 4; ++mt) { va[mt][0] = floatx4{0.f,0.f,0.f,0.f}; va[mt][1] = floatx4{0.f,0.f,0.f,0.f}; }
#pragma unroll
    for (int ks = 0; ks < 6; ++ks) {
        bf16x8 wv0 = *(const bf16x8*)(wcvt + (size_t)(384 + h * 32 + lr) * 192 + ks * 32 + quad * 8);
        bf16x8 wv1 = *(const bf16x8*)(wcvt + (size_t)(384 + h * 32 + 16 + lr) * 192 + ks * 32 + quad * 8);
#pragma unroll
        for (int mt = 0; mt < 4; ++mt) {
            bf16x8 xk = ldx(mt, ks);
            va[mt][0] = MFMA(xk, wv0, va[mt][0], 0, 0, 0);
            va[mt][1] = MFMA(xk, wv1, va[mt][1], 0, 0, 0);
        }
    }
    // vT into P region rows 0..31 (P frags already in regs; DS in-order)
    {
        float bv0 = qkv_b[384 + h * 32 + lr], bv1 = qkv_b[384 + h * 32 + 16 + lr];
#pragma unroll
        for (int mt = 0; mt < 4; ++mt)
#pragma unroll
            for (int r = 0; r < 4; ++r) {
                int tok = mt * 16 + quad * 4 + r;
                R[lr * 72 + tok]        = (bf16_t)(va[mt][0][r] + bv0);
                R[(16 + lr) * 72 + tok] = (bf16_t)(va[mt][1][r] + bv1);
            }
    }

    // ---- PV (64 x 32, K=64) ----
    bf16x8 vf[2][2];
#pragma unroll
    for (int nt = 0; nt < 2; ++nt)
#pragma unroll
        for (int kt = 0; kt < 2; ++kt)
            vf[nt][kt] = *(const bf16x8*)&R[(nt * 16 + lr) * 72 + kt * 32 + quad * 8];
    floatx4 c[4][2];
#pragma unroll
    for (int mt = 0; mt < 4; ++mt) { c[mt][0] = floatx4{0.f,0.f,0.f,0.f}; c[mt][1] = floatx4{0.f,0.f,0.f,0.f}; }
#pragma unroll
    for (int mt = 0; mt < 4; ++mt)
#pragma unroll
        for (int nt = 0; nt < 2; ++nt) {
            c[mt][nt] = MFMA(pf[mt][0], vf[nt][0], c[mt][nt], 0, 0, 0);
            c[mt][nt] = MFMA(pf[mt][1], vf[nt][1], c[mt][nt], 0, 0, 0);
        }
    __syncthreads();   // (2) all XL/R reads done; ctx may overwrite XL

    // ---- ctx -> XL [49][200] (rows >= 49 discarded) ----
#pragma unroll
    for (int mt = 0; mt < 4; ++mt)
#pragma unroll
        for (int nt = 0; nt < 2; ++nt)
#pragma unroll
            for (int r = 0; r < 4; ++r) {
                int tok = mt * 16 + quad * 4 + r;
                if (tok < 49)
                    XL[tok * 200 + h * 32 + nt * 16 + lr] = (bf16_t)c[mt][nt][r];
            }
    __syncthreads();   // (3) ctx of all heads staged

    // ---- folded lin: out = resid + gelu(ctx @ Wf^T + bf), cols [h*32,h*32+32) ----
    floatx4 pr[4][2];
#pragma unroll
    for (int mt = 0; mt < 4; ++mt) { pr[mt][0] = floatx4{0.f,0.f,0.f,0.f}; pr[mt][1] = floatx4{0.f,0.f,0.f,0.f}; }
#pragma unroll
    for (int ks = 0; ks < 6; ++ks) {
        bf16x8 w0 = *(const bf16x8*)(wfo + (size_t)(h * 32 + lr) * 192 + ks * 32 + quad * 8);
        bf16x8 w1 = *(const bf16x8*)(wfo + (size_t)(h * 32 + 16 + lr) * 192 + ks * 32 + quad * 8);
#pragma unroll
        for (int mt = 0; mt < 4; ++mt) {
            bf16x8 af = ldx(mt, ks);   // ctx fragment; rows >= 49 zero
            pr[mt][0] = MFMA(af, w0, pr[mt][0], 0, 0, 0);
            pr[mt][1] = MFMA(af, w1, pr[mt][1], 0, 0, 0);
        }
    }
    // epilogue: bias + gelu + residual, window-reverse + unshift scatter
    {
        float pb0 = bfb[h * 32 + lr], pb1 = bfb[h * 32 + 16 + lr];
#pragma unroll
        for (int mt = 0; mt < 4; ++mt)
#pragma unroll
            for (int r = 0; r < 4; ++r) {
                int m = mt * 16 + quad * 4 + r;
                if (m < 49) {
                    int ii = m / 7, jj = m - ii * 7;
                    int hh2 = whh * 7 + ii + 3; if (hh2 >= 56) hh2 -= 56;
                    int ww2 = www * 7 + jj + 3; if (ww2 >= 56) ww2 -= 56;
                    size_t base2 = ((size_t)(b * 3136 + hh2 * 56 + ww2)) * 192 + h * 32;
                    float v0 = pr[mt][0][r] + pb0;
                    float v1 = pr[mt][1][r] + pb1;
                    float gx0 = 0.5f * v0 * (1.0f + erff(v0 * 0.70710678118654752f));
                    float gx1 = 0.5f * v1 * (1.0f + erff(v1 * 0.70710678118654752f));
                    out[base2 + lr]      = inp[base2 + lr]      + gx0;
                    out[base2 + 16 + lr] = inp[base2 + 16 + lr] + gx1;
                }
            }
    }
}

// ---------------------------------------------------------------------------
extern "C" void kernel_launch(void* const* d_in, const int* in_sizes, int n_in,
                              void* d_out, int out_size, void* d_ws, size_t ws_size,
                              hipStream_t stream)
{
    const float* inp    = (const float*)d_in[0];
    const float* mask   = (const float*)d_in[1];
    const float* g      = (const float*)d_in[2];
    const float* bta    = (const float*)d_in[3];
    const float* qkv_w  = (const float*)d_in[4];
    const float* qkv_b  = (const float*)d_in[5];
    const float* table  = (const float*)d_in[6];
    const int*   rpi    = (const int*)d_in[7];
    const float* proj_w = (const float*)d_in[8];
    const float* proj_b = (const float*)d_in[9];
    const float* lin_w  = (const float*)d_in[10];
    const float* lin_b  = (const float*)d_in[11];
    float* out = (float*)d_out;

    char* ws = (char*)d_ws;
    bf16_t* wcvt = (bf16_t*)(ws);                 // qkv bf16: 221,184 B
    bf16_t* wfo  = wcvt + 110592;                 // folded Wf: 73,728 B
    float*  bfb  = (float*)(ws + 294912);         // folded bias: 768 B
    bf16_t* cb2  = (bf16_t*)(ws + 300032);        // 3,145,728 B (16B aligned)

    prep<<<6768, 256, 0, stream>>>(table, rpi, mask, qkv_w, lin_w, proj_w,
                                   proj_b, lin_b, cb2, wcvt, wfo, bfb);
    fused_window<<<1024, 768, 0, stream>>>(inp, g, bta, wcvt, qkv_b, cb2,
                                           wfo, bfb, out);
}